// Round 1
// baseline (397.146 us; speedup 1.0000x reference)
//
#include <hip/hip_runtime.h>
#include <cstdint>

#define NPIX 3136
#define HGT 56
#define WID 56

// ---------------------------------------------------------------------------
// Generic 1x1-conv GEMM: C[b][m][n] = sum_k W[m][k] * X[b][k][n]
// Tile 64x64, BK=16, 256 threads, each thread computes 4x4 outputs.
// Optional per-output-channel batchnorm.
// ---------------------------------------------------------------------------
__global__ __launch_bounds__(256) void conv1x1_gemm(
    const float* __restrict__ X, const float* __restrict__ W,
    float* __restrict__ C, int M, int K, int N,
    const float* __restrict__ bn_g, const float* __restrict__ bn_b,
    const float* __restrict__ bn_m, const float* __restrict__ bn_v,
    int use_bn)
{
    __shared__ float Ws[16][68];   // [k][m], padded
    __shared__ float Xs[16][64];   // [k][n]

    const int tid = threadIdx.x;
    const int tx = tid & 15;       // n-quad
    const int ty = tid >> 4;       // m-quad
    const int n0 = blockIdx.x * 64;
    const int m0 = blockIdx.y * 64;
    const int b  = blockIdx.z;

    const int wm = tid >> 2;          // 0..63  (m within tile)
    const int wk = (tid & 3) * 4;     // 0,4,8,12
    const int xk = tid >> 4;          // 0..15
    const int xn = (tid & 15) * 4;    // 0..60

    const float* __restrict__ Xb = X + (size_t)b * K * N;

    float acc[4][4];
    #pragma unroll
    for (int i = 0; i < 4; ++i)
        #pragma unroll
        for (int j = 0; j < 4; ++j) acc[i][j] = 0.f;

    for (int k0 = 0; k0 < K; k0 += 16) {
        float4 w4 = *reinterpret_cast<const float4*>(&W[(size_t)(m0 + wm) * K + k0 + wk]);
        float4 x4 = *reinterpret_cast<const float4*>(&Xb[(size_t)(k0 + xk) * N + n0 + xn]);
        __syncthreads();
        Ws[wk + 0][wm] = w4.x;
        Ws[wk + 1][wm] = w4.y;
        Ws[wk + 2][wm] = w4.z;
        Ws[wk + 3][wm] = w4.w;
        *reinterpret_cast<float4*>(&Xs[xk][xn]) = x4;
        __syncthreads();
        #pragma unroll
        for (int kk = 0; kk < 16; ++kk) {
            float4 wr = *reinterpret_cast<const float4*>(&Ws[kk][ty * 4]);
            float4 xr = *reinterpret_cast<const float4*>(&Xs[kk][tx * 4]);
            float wa[4] = {wr.x, wr.y, wr.z, wr.w};
            float xa[4] = {xr.x, xr.y, xr.z, xr.w};
            #pragma unroll
            for (int i = 0; i < 4; ++i)
                #pragma unroll
                for (int j = 0; j < 4; ++j)
                    acc[i][j] += wa[i] * xa[j];
        }
    }

    #pragma unroll
    for (int i = 0; i < 4; ++i) {
        const int m = m0 + ty * 4 + i;
        float sc = 1.f, mu = 0.f, bb = 0.f;
        if (use_bn) {
            sc = bn_g[m] * rsqrtf(bn_v[m] + 1e-5f);
            mu = bn_m[m];
            bb = bn_b[m];
        }
        float4 o;
        o.x = (acc[i][0] - mu) * sc + bb;
        o.y = (acc[i][1] - mu) * sc + bb;
        o.z = (acc[i][2] - mu) * sc + bb;
        o.w = (acc[i][3] - mu) * sc + bb;
        *reinterpret_cast<float4*>(&C[((size_t)b * M + m) * N + n0 + tx * 4]) = o;
    }
}

// ---------------------------------------------------------------------------
// Depthwise 5x5 conv, pad 2. One block per (b, channel) plane.
// ---------------------------------------------------------------------------
__global__ __launch_bounds__(256) void dw5x5(
    const float* __restrict__ in, const float* __restrict__ w,
    float* __restrict__ out)
{
    __shared__ float t[60 * 60];
    const int bc = blockIdx.x;          // b*768 + c
    const int c  = bc % 768;
    const float* __restrict__ ip = in + (size_t)bc * NPIX;
    float* __restrict__ op = out + (size_t)bc * NPIX;
    const int tid = threadIdx.x;

    for (int i = tid; i < 3600; i += 256) {
        int y = i / 60 - 2, x = i % 60 - 2;
        t[i] = (y >= 0 && y < HGT && x >= 0 && x < WID) ? ip[y * WID + x] : 0.f;
    }
    float wv[25];
    #pragma unroll
    for (int j = 0; j < 25; ++j) wv[j] = w[c * 25 + j];
    __syncthreads();

    for (int p = tid; p < NPIX; p += 256) {
        int y = p / WID, x = p % WID;
        float s = 0.f;
        #pragma unroll
        for (int dy = 0; dy < 5; ++dy)
            #pragma unroll
            for (int dx = 0; dx < 5; ++dx)
                s += t[(y + dy) * 60 + (x + dx)] * wv[dy * 5 + dx];
        op[p] = s;
    }
}

// ---------------------------------------------------------------------------
// Grouped pointwise conv: groups=96, 8->8 channels each. One block per (b,g).
// ---------------------------------------------------------------------------
__global__ __launch_bounds__(256) void pw_group(
    const float* __restrict__ in, const float* __restrict__ w,
    float* __restrict__ out)
{
    const int bg = blockIdx.x;
    const int g  = bg % 96;
    const size_t base = (size_t)(bg / 96) * 768 * NPIX + (size_t)(g * 8) * NPIX;
    const float* __restrict__ ip = in + base;
    float* __restrict__ op = out + base;

    float wv[64];
    #pragma unroll
    for (int l = 0; l < 64; ++l) wv[l] = w[(g * 8 + (l >> 3)) * 8 + (l & 7)];

    for (int n = threadIdx.x; n < NPIX; n += 256) {
        float xi[8];
        #pragma unroll
        for (int i = 0; i < 8; ++i) xi[i] = ip[(size_t)i * NPIX + n];
        #pragma unroll
        for (int o = 0; o < 8; ++o) {
            float s = 0.f;
            #pragma unroll
            for (int i = 0; i < 8; ++i) s += wv[o * 8 + i] * xi[i];
            op[(size_t)o * NPIX + n] = s;
        }
    }
}

// ---------------------------------------------------------------------------
// Linear attention per (b, head): kv = sum_n k1 (x) v1 (9x9), then per pixel
// out = (q1 . kv) / (q1 . kv[:,8] + eps) + gelu(bn(v)).  Writes [B][512][N].
// ---------------------------------------------------------------------------
__global__ __launch_bounds__(256) void attn_fuse(
    const float* __restrict__ qkv, const float* __restrict__ tmp,
    const float* __restrict__ pos, const float* __restrict__ scale1p,
    const float* __restrict__ bng, const float* __restrict__ bnb,
    const float* __restrict__ bnm, const float* __restrict__ bnv,
    float* __restrict__ aout)
{
    const int bh = blockIdx.x;
    const int b = bh >> 6, h = bh & 63;
    const float* __restrict__ src = (h < 32)
        ? qkv + ((size_t)b * 768 + h * 24) * NPIX
        : tmp + ((size_t)b * 768 + (h - 32) * 24) * NPIX;
    const float* __restrict__ pp = pos + (size_t)(h * 8) * NPIX;
    const float s1 = scale1p[0];
    const int tid = threadIdx.x, lane = tid & 63, wid = tid >> 6;

    float kv[81];
    #pragma unroll
    for (int i = 0; i < 81; ++i) kv[i] = 0.f;

    // pass 1: accumulate kv = sum_n k1 (x) v1
    for (int n = tid; n < NPIX; n += 256) {
        float k1[9], v1[9];
        #pragma unroll
        for (int c = 0; c < 8; ++c)
            k1[c] = src[(size_t)(8 + c) * NPIX + n] + pp[(size_t)c * NPIX + n];
        #pragma unroll
        for (int c = 0; c < 8; ++c)
            v1[c] = src[(size_t)(16 + c) * NPIX + n];
        float s = 0.f;
        #pragma unroll
        for (int c = 0; c < 8; ++c) s += k1[c] * k1[c];
        float inv = 1.f / (sqrtf(s) + 1e-15f);
        float s2 = 0.f;
        #pragma unroll
        for (int c = 0; c < 8; ++c) { float u = k1[c] * inv; u = u * u; k1[c] = u; s2 += u * u; }
        float inv2 = 1.f / (sqrtf(s2) + 1e-15f);
        #pragma unroll
        for (int c = 0; c < 8; ++c) k1[c] *= inv2;
        k1[8] = s1;
        v1[8] = 1.f;
        #pragma unroll
        for (int c = 0; c < 9; ++c)
            #pragma unroll
            for (int d = 0; d < 9; ++d)
                kv[c * 9 + d] += k1[c] * v1[d];
    }

    // block reduction of the 81 accumulators
    __shared__ float red[4][81];
    __shared__ float kvf[81];
    #pragma unroll
    for (int i = 0; i < 81; ++i) {
        float v = kv[i];
        v += __shfl_down(v, 32);
        v += __shfl_down(v, 16);
        v += __shfl_down(v, 8);
        v += __shfl_down(v, 4);
        v += __shfl_down(v, 2);
        v += __shfl_down(v, 1);
        if (lane == 0) red[wid][i] = v;
    }
    __syncthreads();
    if (tid < 81) kvf[tid] = red[0][tid] + red[1][tid] + red[2][tid] + red[3][tid];
    __syncthreads();
    #pragma unroll
    for (int i = 0; i < 81; ++i) kv[i] = kvf[i];

    float bsc[8], bmu[8], bbe[8];
    #pragma unroll
    for (int d = 0; d < 8; ++d) {
        bsc[d] = bng[d] * rsqrtf(bnv[d] + 1e-5f);
        bmu[d] = bnm[d];
        bbe[d] = bnb[d];
    }

    float* __restrict__ op = aout + ((size_t)b * 512 + h * 8) * NPIX;

    // pass 2: per-pixel output + fused BN+GELU residual
    for (int n = tid; n < NPIX; n += 256) {
        float q1[9];
        #pragma unroll
        for (int c = 0; c < 8; ++c) q1[c] = src[(size_t)c * NPIX + n];
        float s = 0.f;
        #pragma unroll
        for (int c = 0; c < 8; ++c) s += q1[c] * q1[c];
        float inv = 1.f / (sqrtf(s) + 1e-15f);
        float s2 = 0.f;
        #pragma unroll
        for (int c = 0; c < 8; ++c) { float u = q1[c] * inv; u = u * u; q1[c] = u; s2 += u * u; }
        float inv2 = 1.f / (sqrtf(s2) + 1e-15f);
        #pragma unroll
        for (int c = 0; c < 8; ++c) q1[c] *= inv2;
        q1[8] = s1;

        float den = 0.f;
        #pragma unroll
        for (int c = 0; c < 9; ++c) den += q1[c] * kv[c * 9 + 8];
        float invd = 1.f / (den + 1e-15f);

        #pragma unroll
        for (int d = 0; d < 8; ++d) {
            float num = 0.f;
            #pragma unroll
            for (int c = 0; c < 9; ++c) num += q1[c] * kv[c * 9 + d];
            float v = src[(size_t)(16 + d) * NPIX + n];
            float fmv = (v - bmu[d]) * bsc[d] + bbe[d];
            float gel = 0.5f * fmv * (1.f + erff(fmv * 0.70710678118654752f));
            op[(size_t)d * NPIX + n] = num * invd + gel;
        }
    }
}

// ---------------------------------------------------------------------------
extern "C" void kernel_launch(void* const* d_in, const int* in_sizes, int n_in,
                              void* d_out, int out_size, void* d_ws, size_t ws_size,
                              hipStream_t stream)
{
    const float* x      = (const float*)d_in[0];
    const float* w_qkv  = (const float*)d_in[1];
    const float* w_dw   = (const float*)d_in[2];
    const float* w_pw   = (const float*)d_in[3];
    const float* pos    = (const float*)d_in[4];
    const float* s1     = (const float*)d_in[5];
    const float* bng    = (const float*)d_in[6];
    const float* bnb    = (const float*)d_in[7];
    const float* bnm    = (const float*)d_in[8];
    const float* bnv    = (const float*)d_in[9];
    const float* w_proj = (const float*)d_in[10];
    const float* pg     = (const float*)d_in[11];
    const float* pb     = (const float*)d_in[12];
    const float* pm     = (const float*)d_in[13];
    const float* pv     = (const float*)d_in[14];
    float* out = (float*)d_out;

    const int B = 8, N = NPIX;
    const size_t sz = (size_t)B * 768 * N;   // per-buffer float count
    float* qkvb = (float*)d_ws;
    float* dwb  = qkvb + sz;
    float* pwb  = dwb + sz;
    float* attb = dwb;                        // reuse dw buffer for attention out

    // 1. qkv = w_qkv * x   (768x256 GEMM per pixel)
    conv1x1_gemm<<<dim3(N / 64, 768 / 64, B), 256, 0, stream>>>(
        x, w_qkv, qkvb, 768, 256, N, nullptr, nullptr, nullptr, nullptr, 0);

    // 2. depthwise 5x5 pad 2
    dw5x5<<<dim3(B * 768), 256, 0, stream>>>(qkvb, w_dw, dwb);

    // 3. grouped pointwise (96 groups of 8->8)
    pw_group<<<dim3(B * 96), 256, 0, stream>>>(dwb, w_pw, pwb);

    // 4. linear attention + BN + GELU residual -> [B][512][N]
    attn_fuse<<<dim3(B * 64), 256, 0, stream>>>(
        qkvb, pwb, pos, s1, bng, bnb, bnm, bnv, attb);

    // 5. proj 1x1 (256x512) + BN -> out
    conv1x1_gemm<<<dim3(N / 64, 256 / 64, B), 256, 0, stream>>>(
        attb, w_proj, out, 256, 512, N, pg, pb, pm, pv, 1);
}

// Round 2
// 210.914 us; speedup vs baseline: 1.8830x; 1.8830x over previous
//
#include <hip/hip_runtime.h>
#include <cstdint>

#define NPIX 3136
#define HGT 56
#define WID 56
#define NPAD 3200   // padded pixel count for BN=128 tiling

typedef __bf16 bf16x8 __attribute__((ext_vector_type(8)));
typedef __bf16 bf16x4 __attribute__((ext_vector_type(4)));
typedef float  f32x4  __attribute__((ext_vector_type(4)));

typedef const __attribute__((address_space(1))) unsigned int* gptr_t;
typedef __attribute__((address_space(3))) unsigned int* lptr_t;

__device__ __forceinline__ void gload_lds16(const __bf16* g, __bf16* l) {
    __builtin_amdgcn_global_load_lds((gptr_t)(const void*)g, (lptr_t)(void*)l, 16, 0, 0);
}

// ---------------------------------------------------------------------------
// Convert both weight matrices to bf16 (row-major, k contiguous).
// ---------------------------------------------------------------------------
__global__ __launch_bounds__(256) void wcvt(
    const float* __restrict__ wq, const float* __restrict__ wp,
    __bf16* __restrict__ oq, __bf16* __restrict__ op)
{
    int i = blockIdx.x * 256 + threadIdx.x;
    if (i < 768 * 256) oq[i] = (__bf16)wq[i];
    if (i < 256 * 512) op[i] = (__bf16)wp[i];
}

// ---------------------------------------------------------------------------
// x [8][256][3136] f32 -> xT [8][3200][256] bf16 (n-major), zero-padded rows.
// ---------------------------------------------------------------------------
__global__ __launch_bounds__(256) void xpose_cvt(
    const float* __restrict__ x, __bf16* __restrict__ xT)
{
    __shared__ float t[32][33];
    const int n0 = blockIdx.x * 32;   // 0..3168
    const int k0 = blockIdx.y * 32;   // 0..224
    const int b  = blockIdx.z;
    const int tid = threadIdx.x;
    const int ln = tid & 31, lk = tid >> 5;   // 8 k-rows per pass
    #pragma unroll
    for (int r = 0; r < 4; ++r) {
        int n = n0 + ln, k = k0 + lk + r * 8;
        t[lk + r * 8][ln] = (n < NPIX) ? x[((size_t)b * 256 + k) * NPIX + n] : 0.f;
    }
    __syncthreads();
    const int nr = tid >> 3, kc = (tid & 7) * 4;
    bf16x4 o;
    #pragma unroll
    for (int i = 0; i < 4; ++i) o[i] = (__bf16)t[kc + i][nr];
    *(bf16x4*)&xT[((size_t)b * NPAD + n0 + nr) * 256 + k0 + kc] = o;
}

// ---------------------------------------------------------------------------
// bf16 MFMA GEMM: C[b][m][n] = sum_k A[m][k] * B[b][n][k]
// BM=128, BK=32, 4 waves. BN template (128 for qkv, 64 for proj).
// MODE 0: bf16 planar out.  MODE 1: f32 planar out + BN.
// ---------------------------------------------------------------------------
template<int BN, int MODE>
__global__ __launch_bounds__(256) void gemm1x1(
    const __bf16* __restrict__ A,   // [M][K]
    const __bf16* __restrict__ Bm,  // [batch][NP][K]
    void* __restrict__ Cout,
    const int M, const int K, const int N, const int NP,
    const float* __restrict__ bn_g, const float* __restrict__ bn_b,
    const float* __restrict__ bn_m, const float* __restrict__ bn_v)
{
    constexpr int NF = BN / 32 / 2 * 2 / 2;   // frags per wave in N = BN/32... keep explicit below
    constexpr int NFRAG = BN / 32;            // wave-tile N = BN/2 -> BN/32 fragments
    (void)NF;
    __shared__ __bf16 As[128 * 32];
    __shared__ __bf16 Bs[BN * 32];
    const int tid = threadIdx.x;
    const int n0 = blockIdx.x * BN, m0 = blockIdx.y * 128;
    const int b = blockIdx.z;
    const int lane = tid & 63, wid = tid >> 6;
    const int wr = wid >> 1, wc = wid & 1;
    const int lr = lane & 15, lk = (lane >> 4) * 8;

    f32x4 acc[4][NFRAG] = {};
    const __bf16* Ap = A + (size_t)m0 * K;
    const __bf16* Bp = Bm + ((size_t)b * NP + n0) * K;
    const int ar = tid >> 2, ac = (tid & 3) * 8;

    for (int k0 = 0; k0 < K; k0 += 32) {
        __syncthreads();   // all waves done reading previous tiles
        gload_lds16(Ap + (size_t)ar * K + k0 + ac,          As + ar * 32 + ac);
        gload_lds16(Ap + (size_t)(ar + 64) * K + k0 + ac,   As + (ar + 64) * 32 + ac);
        #pragma unroll
        for (int i = 0; i < BN / 64; ++i)
            gload_lds16(Bp + (size_t)(ar + i * 64) * K + k0 + ac, Bs + (ar + i * 64) * 32 + ac);
        __syncthreads();   // compiler drains vmcnt before s_barrier

        bf16x8 af[4], bfr[NFRAG];
        #pragma unroll
        for (int i = 0; i < 4; ++i)
            af[i] = *(const bf16x8*)(As + (wr * 64 + i * 16 + lr) * 32 + lk);
        #pragma unroll
        for (int j = 0; j < NFRAG; ++j)
            bfr[j] = *(const bf16x8*)(Bs + (wc * (BN / 2) + j * 16 + lr) * 32 + lk);
        #pragma unroll
        for (int i = 0; i < 4; ++i)
            #pragma unroll
            for (int j = 0; j < NFRAG; ++j)
                acc[i][j] = __builtin_amdgcn_mfma_f32_16x16x32_bf16(af[i], bfr[j], acc[i][j], 0, 0, 0);
    }

    const int rbase = (lane >> 4) * 4;
    if (MODE == 0) {
        __bf16* C = (__bf16*)Cout + (size_t)b * M * N;
        #pragma unroll
        for (int i = 0; i < 4; ++i) {
            #pragma unroll
            for (int r = 0; r < 4; ++r) {
                const int m = m0 + wr * 64 + i * 16 + rbase + r;
                #pragma unroll
                for (int j = 0; j < NFRAG; ++j) {
                    const int n = n0 + wc * (BN / 2) + j * 16 + lr;
                    if (n < N) C[(size_t)m * N + n] = (__bf16)acc[i][j][r];
                }
            }
        }
    } else {
        float* C = (float*)Cout + (size_t)b * M * N;
        #pragma unroll
        for (int i = 0; i < 4; ++i) {
            #pragma unroll
            for (int r = 0; r < 4; ++r) {
                const int m = m0 + wr * 64 + i * 16 + rbase + r;
                const float sc = bn_g[m] * rsqrtf(bn_v[m] + 1e-5f);
                const float mu = bn_m[m], bb = bn_b[m];
                #pragma unroll
                for (int j = 0; j < NFRAG; ++j) {
                    const int n = n0 + wc * (BN / 2) + j * 16 + lr;
                    if (n < N) C[(size_t)m * N + n] = (acc[i][j][r] - mu) * sc + bb;
                }
            }
        }
    }
}

// ---------------------------------------------------------------------------
// Depthwise 5x5 conv pad 2, bf16 I/O, register sliding window (5 LDS reads/px).
// ---------------------------------------------------------------------------
__global__ __launch_bounds__(256) void dw5x5(
    const __bf16* __restrict__ in, const float* __restrict__ w,
    __bf16* __restrict__ out)
{
    __shared__ float t[60 * 60];
    const int bc = blockIdx.x;
    const int c  = bc % 768;
    const __bf16* __restrict__ ip = in + (size_t)bc * NPIX;
    __bf16* __restrict__ op = out + (size_t)bc * NPIX;
    const int tid = threadIdx.x;

    for (int i = tid; i < 3600; i += 256) {
        int y = i / 60 - 2, x = i % 60 - 2;
        t[i] = (y >= 0 && y < HGT && x >= 0 && x < WID) ? (float)ip[y * WID + x] : 0.f;
    }
    float wv[25];
    #pragma unroll
    for (int j = 0; j < 25; ++j) wv[j] = w[c * 25 + j];
    __syncthreads();

    const int x  = tid & 63;
    const int y0 = (tid >> 6) * 14;
    if (x < WID) {
        float win[5][5];
        #pragma unroll
        for (int r = 0; r < 4; ++r)
            #pragma unroll
            for (int cc = 0; cc < 5; ++cc)
                win[r][cc] = t[(y0 + r) * 60 + x + cc];
        #pragma unroll
        for (int i = 0; i < 14; ++i) {
            #pragma unroll
            for (int cc = 0; cc < 5; ++cc)
                win[4][cc] = t[(y0 + i + 4) * 60 + x + cc];
            float s = 0.f;
            #pragma unroll
            for (int r = 0; r < 5; ++r)
                #pragma unroll
                for (int cc = 0; cc < 5; ++cc)
                    s += win[r][cc] * wv[r * 5 + cc];
            op[(y0 + i) * WID + x] = (__bf16)s;
            #pragma unroll
            for (int r = 0; r < 4; ++r)
                #pragma unroll
                for (int cc = 0; cc < 5; ++cc)
                    win[r][cc] = win[r + 1][cc];
        }
    }
}

// ---------------------------------------------------------------------------
// Grouped pointwise conv, 96 groups of 8->8, bf16 I/O.
// ---------------------------------------------------------------------------
__global__ __launch_bounds__(256) void pw_group(
    const __bf16* __restrict__ in, const float* __restrict__ w,
    __bf16* __restrict__ out)
{
    const int bg = blockIdx.x;
    const int g  = bg % 96;
    const size_t base = (size_t)(bg / 96) * 768 * NPIX + (size_t)(g * 8) * NPIX;
    const __bf16* __restrict__ ip = in + base;
    __bf16* __restrict__ op = out + base;

    float wv[64];
    #pragma unroll
    for (int l = 0; l < 64; ++l) wv[l] = w[(g * 8 + (l >> 3)) * 8 + (l & 7)];

    for (int n = threadIdx.x; n < NPIX; n += 256) {
        float xi[8];
        #pragma unroll
        for (int i = 0; i < 8; ++i) xi[i] = (float)ip[(size_t)i * NPIX + n];
        #pragma unroll
        for (int o = 0; o < 8; ++o) {
            float s = 0.f;
            #pragma unroll
            for (int i = 0; i < 8; ++i) s += wv[o * 8 + i] * xi[i];
            op[(size_t)o * NPIX + n] = (__bf16)s;
        }
    }
}

// ---------------------------------------------------------------------------
// Attention stage A: kv[b*64+h][81] = sum_n k1 (x) v1
// ---------------------------------------------------------------------------
__global__ __launch_bounds__(512) void attn_kv(
    const __bf16* __restrict__ qkvb, const __bf16* __restrict__ pwb,
    const float* __restrict__ pos, const float* __restrict__ s1p,
    float* __restrict__ kvbuf)
{
    const int bh = blockIdx.x;
    const int b = bh >> 6, h = bh & 63;
    const __bf16* __restrict__ src = (h < 32)
        ? qkvb + ((size_t)b * 768 + h * 24) * NPIX
        : pwb  + ((size_t)b * 768 + (h - 32) * 24) * NPIX;
    const float* __restrict__ pp = pos + (size_t)(h * 8) * NPIX;
    const float s1 = s1p[0];
    const int tid = threadIdx.x, lane = tid & 63, wid = tid >> 6;

    float kv[81];
    #pragma unroll
    for (int i = 0; i < 81; ++i) kv[i] = 0.f;

    for (int n = tid; n < NPIX; n += 512) {
        float k1[9], v1[9];
        #pragma unroll
        for (int c = 0; c < 8; ++c)
            k1[c] = (float)src[(size_t)(8 + c) * NPIX + n] + pp[(size_t)c * NPIX + n];
        #pragma unroll
        for (int c = 0; c < 8; ++c)
            v1[c] = (float)src[(size_t)(16 + c) * NPIX + n];
        float s = 0.f;
        #pragma unroll
        for (int c = 0; c < 8; ++c) s += k1[c] * k1[c];
        float inv = 1.f / (sqrtf(s) + 1e-15f);
        float s2 = 0.f;
        #pragma unroll
        for (int c = 0; c < 8; ++c) { float u = k1[c] * inv; u = u * u; k1[c] = u; s2 += u * u; }
        float inv2 = 1.f / (sqrtf(s2) + 1e-15f);
        #pragma unroll
        for (int c = 0; c < 8; ++c) k1[c] *= inv2;
        k1[8] = s1;
        v1[8] = 1.f;
        #pragma unroll
        for (int c = 0; c < 9; ++c)
            #pragma unroll
            for (int d = 0; d < 9; ++d)
                kv[c * 9 + d] += k1[c] * v1[d];
    }

    __shared__ float red[8][81];
    #pragma unroll
    for (int i = 0; i < 81; ++i) {
        float v = kv[i];
        v += __shfl_down(v, 32);
        v += __shfl_down(v, 16);
        v += __shfl_down(v, 8);
        v += __shfl_down(v, 4);
        v += __shfl_down(v, 2);
        v += __shfl_down(v, 1);
        if (lane == 0) red[wid][i] = v;
    }
    __syncthreads();
    if (tid < 81) {
        float s = 0.f;
        #pragma unroll
        for (int wdx = 0; wdx < 8; ++wdx) s += red[wdx][tid];
        kvbuf[(size_t)bh * 81 + tid] = s;
    }
}

// ---------------------------------------------------------------------------
// Attention stage B: per pixel-slab, per head-quarter: out = q1.kv/den + gelu(bn(v))
// Writes attb [b][n][512] bf16 (k-contiguous for the proj GEMM).
// ---------------------------------------------------------------------------
__global__ __launch_bounds__(256) void attn_out(
    const __bf16* __restrict__ qkvb, const __bf16* __restrict__ pwb,
    const float* __restrict__ kvbuf,
    const float* __restrict__ bng, const float* __restrict__ bnb,
    const float* __restrict__ bnm, const float* __restrict__ bnv,
    const float* __restrict__ s1p, __bf16* __restrict__ attb)
{
    __shared__ float kvs[16 * 81];
    const int b = blockIdx.y, qz = blockIdx.z;
    const int n = blockIdx.x * 64 + (threadIdx.x & 63);
    const int sub = threadIdx.x >> 6;   // 0..3
    for (int i = threadIdx.x; i < 16 * 81; i += 256)
        kvs[i] = kvbuf[((size_t)b * 64 + qz * 16) * 81 + i];
    __syncthreads();

    float bsc[8], bmu[8], bbe[8];
    #pragma unroll
    for (int d = 0; d < 8; ++d) {
        bsc[d] = bng[d] * rsqrtf(bnv[d] + 1e-5f);
        bmu[d] = bnm[d];
        bbe[d] = bnb[d];
    }
    const float s1 = s1p[0];

    #pragma unroll
    for (int hh = 0; hh < 4; ++hh) {
        const int h = qz * 16 + sub * 4 + hh;
        const float* kvh = &kvs[(sub * 4 + hh) * 81];
        const __bf16* __restrict__ src = (h < 32)
            ? qkvb + ((size_t)b * 768 + h * 24) * NPIX
            : pwb  + ((size_t)b * 768 + (h - 32) * 24) * NPIX;

        float q1[9];
        #pragma unroll
        for (int c = 0; c < 8; ++c) q1[c] = (float)src[(size_t)c * NPIX + n];
        float s = 0.f;
        #pragma unroll
        for (int c = 0; c < 8; ++c) s += q1[c] * q1[c];
        float inv = 1.f / (sqrtf(s) + 1e-15f);
        float s2 = 0.f;
        #pragma unroll
        for (int c = 0; c < 8; ++c) { float u = q1[c] * inv; u = u * u; q1[c] = u; s2 += u * u; }
        float inv2 = 1.f / (sqrtf(s2) + 1e-15f);
        #pragma unroll
        for (int c = 0; c < 8; ++c) q1[c] *= inv2;
        q1[8] = s1;

        float den = 0.f;
        #pragma unroll
        for (int c = 0; c < 9; ++c) den += q1[c] * kvh[c * 9 + 8];
        const float invd = 1.f / (den + 1e-15f);

        bf16x8 o;
        #pragma unroll
        for (int d = 0; d < 8; ++d) {
            float num = 0.f;
            #pragma unroll
            for (int c = 0; c < 9; ++c) num += q1[c] * kvh[c * 9 + d];
            float v = (float)src[(size_t)(16 + d) * NPIX + n];
            float fmv = (v - bmu[d]) * bsc[d] + bbe[d];
            float gel = 0.5f * fmv * (1.f + erff(fmv * 0.70710678118654752f));
            o[d] = (__bf16)(num * invd + gel);
        }
        *(bf16x8*)&attb[((size_t)b * NPIX + n) * 512 + h * 8] = o;
    }
}

// ---------------------------------------------------------------------------
extern "C" void kernel_launch(void* const* d_in, const int* in_sizes, int n_in,
                              void* d_out, int out_size, void* d_ws, size_t ws_size,
                              hipStream_t stream)
{
    const float* x      = (const float*)d_in[0];
    const float* w_qkv  = (const float*)d_in[1];
    const float* w_dw   = (const float*)d_in[2];
    const float* w_pw   = (const float*)d_in[3];
    const float* pos    = (const float*)d_in[4];
    const float* s1     = (const float*)d_in[5];
    const float* bng    = (const float*)d_in[6];
    const float* bnb    = (const float*)d_in[7];
    const float* bnm    = (const float*)d_in[8];
    const float* bnv    = (const float*)d_in[9];
    const float* w_proj = (const float*)d_in[10];
    const float* pg     = (const float*)d_in[11];
    const float* pb     = (const float*)d_in[12];
    const float* pm     = (const float*)d_in[13];
    const float* pv     = (const float*)d_in[14];
    float* out = (float*)d_out;

    char* w = (char*)d_ws;
    __bf16* xT    = (__bf16*)(w);                       // 8*3200*256*2   = 13,107,200
    __bf16* qkvb  = (__bf16*)(w + 13107200);            // 8*768*3136*2   = 38,535,168
    __bf16* dwb   = (__bf16*)(w + 51642368);            // 38,535,168
    __bf16* pwb   = (__bf16*)(w + 90177536);            // 38,535,168
    __bf16* attb  = (__bf16*)(w + 128712704);           // 8*3136*512*2   = 25,690,112
    float*  kvbuf = (float*) (w + 154402816);           // 512*81*4       = 165,888
    __bf16* wq_bf = (__bf16*)(w + 154568704);           // 768*256*2      = 393,216
    __bf16* wp_bf = (__bf16*)(w + 154961920);           // 256*512*2      = 262,144

    wcvt<<<768, 256, 0, stream>>>(w_qkv, w_proj, wq_bf, wp_bf);
    xpose_cvt<<<dim3(100, 8, 8), 256, 0, stream>>>(x, xT);

    // qkv = w_qkv(768x256) @ x  -> bf16 planar [8][768][3136]
    gemm1x1<128, 0><<<dim3(25, 6, 8), 256, 0, stream>>>(
        wq_bf, xT, qkvb, 768, 256, NPIX, NPAD,
        nullptr, nullptr, nullptr, nullptr);

    dw5x5<<<dim3(8 * 768), 256, 0, stream>>>(qkvb, w_dw, dwb);
    pw_group<<<dim3(8 * 96), 256, 0, stream>>>(dwb, w_pw, pwb);

    attn_kv<<<dim3(8 * 64), 512, 0, stream>>>(qkvb, pwb, pos, s1, kvbuf);
    attn_out<<<dim3(49, 8, 4), 256, 0, stream>>>(
        qkvb, pwb, kvbuf, bng, bnb, bnm, bnv, s1, attb);

    // out = w_proj(256x512) @ attb^T  + BN -> f32 planar [8][256][3136]
    gemm1x1<64, 1><<<dim3(49, 2, 8), 256, 0, stream>>>(
        wp_bf, attb, out, 256, 512, NPIX, NPIX,
        pg, pb, pm, pv);
}